// Round 2
// baseline (1436.294 us; speedup 1.0000x reference)
//
#include <hip/hip_runtime.h>

// GCNConv: out = D^-1/2 (A+I) D^-1/2 X W + b
// N=100000, E=1600000, Din=Dout=128; x/W/b fp32, edge_index int32, out fp32.
//
// R6: single-level sort + fused bucket aggregation.
//     - buckets of 64 nodes; hist/scan/place sorts edges by bucket only
//       (payload ((c&63)<<17 | row, w)); weighted degree via global f32
//       atomics folded into k_place; k_dis computes rsqrt.
//     - k_agg (replaces k_fine + k_gather): one block per bucket, output
//       accumulated in 32 KB LDS (accL/accH[64][64], 2-way bank = free),
//       1 edge/wave with unroll-8 coalesced 256B h-row loads (R4 pattern),
//       ds_add_f32 atomics, fused self-loop + bias epilogue.
//     Eliminates: fine pass (2 srw re-reads + spack scatter), spack
//     re-read in gather, rowptr.

#define ELEMS_PER_SCAN_BLOCK 4096  // 256 threads * 16
#define CHUNK 4096                 // edges per hist/place block

typedef __attribute__((ext_vector_type(8))) short short8;
typedef __attribute__((ext_vector_type(4))) float f32x4;

__device__ inline unsigned short f2bf(float f) {  // fp32 -> bf16 RNE
    unsigned u = __float_as_uint(f);
    u += 0x7fffu + ((u >> 16) & 1u);
    return (unsigned short)(u >> 16);
}
__device__ inline float bf_lo(unsigned u) { return __uint_as_float(u << 16); }
__device__ inline float bf_hi(unsigned u) { return __uint_as_float(u & 0xffff0000u); }

// ---- coarse histogram (64-node buckets) + degf zero-init ----
__global__ __launch_bounds__(256) void k_hist(const int* __restrict__ col,
                                              int* __restrict__ histg,
                                              float* __restrict__ degf,
                                              int E, int N, int NC, int NBLK) {
    __shared__ int lh[2048];
    int t = threadIdx.x, blk = blockIdx.x;
    for (int i = t; i < 2048; i += 256) lh[i] = 0;
    // zero degf (grid-stride; this dispatch completes before k_place runs)
    for (int i = blk * 256 + t; i < N; i += NBLK * 256) degf[i] = 0.f;
    __syncthreads();
    int base = blk * CHUNK;
    #pragma unroll
    for (int i = 0; i < CHUNK / 256; ++i) {
        int e = base + i * 256 + t;
        if (e < E) atomicAdd(&lh[col[e] >> 6], 1);
    }
    __syncthreads();
    for (int b = t; b < NC; b += 256) histg[b * NBLK + blk] = lh[b];
}

// ---- scan (3 kernels) ----
__device__ inline int wave_incl_scan(int x, int lane) {
    #pragma unroll
    for (int d = 1; d < 64; d <<= 1) {
        int y = __shfl_up(x, d, 64);
        if (lane >= d) x += y;
    }
    return x;
}

__global__ void k_scan1(const int* __restrict__ in, int* __restrict__ out,
                        int* __restrict__ bsum, int M) {
    __shared__ int wsum[4];
    __shared__ int woff[4];
    int t = threadIdx.x, lane = t & 63, wid = t >> 6;
    int base = blockIdx.x * ELEMS_PER_SCAN_BLOCK + t * 16;
    int v[16];
    #pragma unroll
    for (int i = 0; i < 16; ++i) v[i] = (base + i < M) ? in[base + i] : 0;
    int run = 0;
    #pragma unroll
    for (int i = 0; i < 16; ++i) { int x = v[i]; v[i] = run; run += x; }
    int incl = wave_incl_scan(run, lane);
    int excl = incl - run;
    if (lane == 63) wsum[wid] = incl;
    __syncthreads();
    if (t == 0) {
        int r = 0;
        #pragma unroll
        for (int w = 0; w < 4; ++w) { int s = wsum[w]; woff[w] = r; r += s; }
        bsum[blockIdx.x] = r;
    }
    __syncthreads();
    int off = woff[wid] + excl;
    #pragma unroll
    for (int i = 0; i < 16; ++i)
        if (base + i < M) out[base + i] = v[i] + off;
}

__global__ void k_scan2(const int* __restrict__ bsum, int* __restrict__ boff, int NB) {
    __shared__ int wsum[4];
    __shared__ int woff[4];
    int t = threadIdx.x, lane = t & 63, wid = t >> 6;
    int x = (t < NB) ? bsum[t] : 0;
    int incl = wave_incl_scan(x, lane);
    int excl = incl - x;
    if (lane == 63) wsum[wid] = incl;
    __syncthreads();
    if (t == 0) {
        int r = 0;
        #pragma unroll
        for (int w = 0; w < 4; ++w) { int s = wsum[w]; woff[w] = r; r += s; }
    }
    __syncthreads();
    if (t < NB) boff[t] = woff[wid] + excl;
}

__global__ void k_scan3(int* __restrict__ arr, const int* __restrict__ boff, int M) {
    int t = threadIdx.x;
    int base = blockIdx.x * ELEMS_PER_SCAN_BLOCK + t * 16;
    int off = boff[blockIdx.x];
    #pragma unroll
    for (int i = 0; i < 16; ++i) {
        int idx = base + i;
        if (idx < M) arr[idx] += off;
    }
}

// ---- placement: LDS cursors; payload ((c&63)<<17|row, w); + weighted degree ----
__global__ __launch_bounds__(256) void k_place(const int* __restrict__ row,
                                               const int* __restrict__ col,
                                               const float* __restrict__ wgt,
                                               const int* __restrict__ histg,
                                               int2* __restrict__ srw,
                                               float* __restrict__ degf,
                                               int E, int NC, int NBLK) {
    __shared__ int lo[2048];
    int t = threadIdx.x, blk = blockIdx.x;
    for (int b = t; b < NC; b += 256) lo[b] = histg[b * NBLK + blk];
    __syncthreads();
    int base = blk * CHUNK;
    #pragma unroll
    for (int i = 0; i < CHUNK / 256; ++i) {
        int e = base + i * 256 + t;
        if (e < E) {
            int c = col[e];
            float w = wgt[e];
            int pos = atomicAdd(&lo[c >> 6], 1);
            srw[pos] = make_int2(((c & 63) << 17) | row[e], __float_as_int(w));
            atomicAdd(&degf[c], w);
        }
    }
}

// ---- dis = rsqrt(degf + 1) ----
__global__ void k_dis(const float* __restrict__ degf, float* __restrict__ dis, int N) {
    int i = blockIdx.x * 256 + threadIdx.x;
    if (i < N) dis[i] = rsqrtf(degf[i] + 1.0f);
}

// ---- W transpose + bf16 convert ----
__global__ void k_wprep(const float* __restrict__ W, unsigned short* __restrict__ Wtg) {
    int n = blockIdx.x;
    int k = threadIdx.x;
    Wtg[n * 128 + k] = f2bf(W[k * 128 + n]);
}

// ---- h = x @ W, bf16 MFMA 16x16x32. 64 rows x 128 cols / block, 4 waves. ----
__global__ __launch_bounds__(256) void k_gemm(const float* __restrict__ x,
                                              const unsigned short* __restrict__ Wtg,
                                              unsigned short* __restrict__ h, int N) {
    __shared__ short Xs[64][136];
    __shared__ short Ws[128][136];
    int t = threadIdx.x;
    int lane = t & 63, wid = t >> 6;
    int row0 = blockIdx.x * 64;
    {
        int r = t >> 2;
        int kseg = (t & 3) * 32;
        int gr = row0 + r;
        const float4* src = (const float4*)(x + (size_t)gr * 128 + kseg);
        #pragma unroll
        for (int i = 0; i < 4; ++i) {
            float4 v0 = make_float4(0.f, 0.f, 0.f, 0.f), v1 = v0;
            if (gr < N) { v0 = src[2 * i]; v1 = src[2 * i + 1]; }
            short8 p;
            p[0] = (short)f2bf(v0.x); p[1] = (short)f2bf(v0.y);
            p[2] = (short)f2bf(v0.z); p[3] = (short)f2bf(v0.w);
            p[4] = (short)f2bf(v1.x); p[5] = (short)f2bf(v1.y);
            p[6] = (short)f2bf(v1.z); p[7] = (short)f2bf(v1.w);
            *(short8*)&Xs[r][kseg + 8 * i] = p;
        }
    }
    {
        int n = t >> 1;
        int seg = (t & 1) * 64;
        const short* wsrc = (const short*)Wtg + n * 128 + seg;
        #pragma unroll
        for (int i = 0; i < 8; ++i)
            *(short8*)&Ws[n][seg + 8 * i] = *(const short8*)(wsrc + 8 * i);
    }
    __syncthreads();

    int q = lane >> 4;
    int m = lane & 15;
    f32x4 acc[8];
    #pragma unroll
    for (int tde = 0; tde < 8; ++tde) acc[tde] = (f32x4){0.f, 0.f, 0.f, 0.f};
    #pragma unroll
    for (int kc = 0; kc < 128; kc += 32) {
        short8 af = *(const short8*)&Xs[wid * 16 + m][kc + q * 8];
        #pragma unroll
        for (int tde = 0; tde < 8; ++tde) {
            short8 bf = *(const short8*)&Ws[tde * 16 + m][kc + q * 8];
            acc[tde] = __builtin_amdgcn_mfma_f32_16x16x32_bf16(af, bf, acc[tde], 0, 0, 0);
        }
    }
    #pragma unroll
    for (int r = 0; r < 4; ++r) {
        int grow = row0 + wid * 16 + q * 4 + r;
        if (grow < N) {
            #pragma unroll
            for (int tde = 0; tde < 8; ++tde)
                h[(size_t)grow * 128 + tde * 16 + m] = f2bf(acc[tde][r]);
        }
    }
}

// ---- fused bucket aggregation: 1 block per 64-node bucket, LDS fp32 acc.
//      1 edge/wave, unroll 8 (8 coalesced 256B h-rows in flight), ds_add_f32.
//      Epilogue fuses self-loop + bias + out write. ----
__global__ __launch_bounds__(256) void k_agg(const int* __restrict__ histg,
                                             const long* __restrict__ srwl,
                                             const unsigned int* __restrict__ hb,
                                             const float* __restrict__ dis,
                                             const float* __restrict__ bias,
                                             float* __restrict__ out,
                                             int E, int N, int NC, int NBLK) {
    __shared__ float accL[64][64];  // even cols: accL[c][lane] = col 2*lane
    __shared__ float accH[64][64];  // odd  cols
    int t = threadIdx.x, lane = t & 63, wid = t >> 6;
    int b = blockIdx.x;
    int nb = b << 6;
    int start = histg[b * NBLK];
    int end = (b == NC - 1) ? E : histg[(b + 1) * NBLK];

    {
        f32x4 z = (f32x4){0.f, 0.f, 0.f, 0.f};
        f32x4* aL = (f32x4*)&accL[0][0];
        f32x4* aH = (f32x4*)&accH[0][0];
        #pragma unroll
        for (int i = 0; i < 4; ++i) { aL[t + i * 256] = z; aH[t + i * 256] = z; }
    }
    __syncthreads();

    for (int j0 = start + wid * 8; j0 < end; j0 += 32) {
        long q0, q1, q2, q3, q4, q5, q6, q7;
        {
            int le = end - 1;
            q0 = srwl[j0 + 0 < end ? j0 + 0 : le];
            q1 = srwl[j0 + 1 < end ? j0 + 1 : le];
            q2 = srwl[j0 + 2 < end ? j0 + 2 : le];
            q3 = srwl[j0 + 3 < end ? j0 + 3 : le];
            q4 = srwl[j0 + 4 < end ? j0 + 4 : le];
            q5 = srwl[j0 + 5 < end ? j0 + 5 : le];
            q6 = srwl[j0 + 6 < end ? j0 + 6 : le];
            q7 = srwl[j0 + 7 < end ? j0 + 7 : le];
        }
        int r0 = __builtin_amdgcn_readfirstlane((int)q0 & 0x1FFFF);
        int r1 = __builtin_amdgcn_readfirstlane((int)q1 & 0x1FFFF);
        int r2 = __builtin_amdgcn_readfirstlane((int)q2 & 0x1FFFF);
        int r3 = __builtin_amdgcn_readfirstlane((int)q3 & 0x1FFFF);
        int r4 = __builtin_amdgcn_readfirstlane((int)q4 & 0x1FFFF);
        int r5 = __builtin_amdgcn_readfirstlane((int)q5 & 0x1FFFF);
        int r6 = __builtin_amdgcn_readfirstlane((int)q6 & 0x1FFFF);
        int r7 = __builtin_amdgcn_readfirstlane((int)q7 & 0x1FFFF);
        unsigned u0 = hb[(size_t)r0 * 64 + lane];
        unsigned u1 = hb[(size_t)r1 * 64 + lane];
        unsigned u2 = hb[(size_t)r2 * 64 + lane];
        unsigned u3 = hb[(size_t)r3 * 64 + lane];
        unsigned u4 = hb[(size_t)r4 * 64 + lane];
        unsigned u5 = hb[(size_t)r5 * 64 + lane];
        unsigned u6 = hb[(size_t)r6 * 64 + lane];
        unsigned u7 = hb[(size_t)r7 * 64 + lane];
        float a0 = (j0 + 0 < end) ? dis[r0] * __uint_as_float((unsigned)((unsigned long)q0 >> 32)) : 0.f;
        float a1 = (j0 + 1 < end) ? dis[r1] * __uint_as_float((unsigned)((unsigned long)q1 >> 32)) : 0.f;
        float a2 = (j0 + 2 < end) ? dis[r2] * __uint_as_float((unsigned)((unsigned long)q2 >> 32)) : 0.f;
        float a3 = (j0 + 3 < end) ? dis[r3] * __uint_as_float((unsigned)((unsigned long)q3 >> 32)) : 0.f;
        float a4 = (j0 + 4 < end) ? dis[r4] * __uint_as_float((unsigned)((unsigned long)q4 >> 32)) : 0.f;
        float a5 = (j0 + 5 < end) ? dis[r5] * __uint_as_float((unsigned)((unsigned long)q5 >> 32)) : 0.f;
        float a6 = (j0 + 6 < end) ? dis[r6] * __uint_as_float((unsigned)((unsigned long)q6 >> 32)) : 0.f;
        float a7 = (j0 + 7 < end) ? dis[r7] * __uint_as_float((unsigned)((unsigned long)q7 >> 32)) : 0.f;
        int c0 = __builtin_amdgcn_readfirstlane(((int)q0 >> 17) & 63);
        int c1 = __builtin_amdgcn_readfirstlane(((int)q1 >> 17) & 63);
        int c2 = __builtin_amdgcn_readfirstlane(((int)q2 >> 17) & 63);
        int c3 = __builtin_amdgcn_readfirstlane(((int)q3 >> 17) & 63);
        int c4 = __builtin_amdgcn_readfirstlane(((int)q4 >> 17) & 63);
        int c5 = __builtin_amdgcn_readfirstlane(((int)q5 >> 17) & 63);
        int c6 = __builtin_amdgcn_readfirstlane(((int)q6 >> 17) & 63);
        int c7 = __builtin_amdgcn_readfirstlane(((int)q7 >> 17) & 63);
        atomicAdd(&accL[c0][lane], a0 * bf_lo(u0)); atomicAdd(&accH[c0][lane], a0 * bf_hi(u0));
        atomicAdd(&accL[c1][lane], a1 * bf_lo(u1)); atomicAdd(&accH[c1][lane], a1 * bf_hi(u1));
        atomicAdd(&accL[c2][lane], a2 * bf_lo(u2)); atomicAdd(&accH[c2][lane], a2 * bf_hi(u2));
        atomicAdd(&accL[c3][lane], a3 * bf_lo(u3)); atomicAdd(&accH[c3][lane], a3 * bf_hi(u3));
        atomicAdd(&accL[c4][lane], a4 * bf_lo(u4)); atomicAdd(&accH[c4][lane], a4 * bf_hi(u4));
        atomicAdd(&accL[c5][lane], a5 * bf_lo(u5)); atomicAdd(&accH[c5][lane], a5 * bf_hi(u5));
        atomicAdd(&accL[c6][lane], a6 * bf_lo(u6)); atomicAdd(&accH[c6][lane], a6 * bf_hi(u6));
        atomicAdd(&accL[c7][lane], a7 * bf_lo(u7)); atomicAdd(&accH[c7][lane], a7 * bf_hi(u7));
    }
    __syncthreads();

    // epilogue: out[n] = b + dn*(acc[n] + dn*h[n]); 16 rows per wave
    float2 bv = *(const float2*)(bias + 2 * lane);
    for (int n = wid; n < 64; n += 4) {
        int gn = nb + n;
        if (gn >= N) break;
        float dn = dis[gn];
        unsigned us = hb[(size_t)gn * 64 + lane];
        float oL = bv.x + dn * (accL[n][lane] + dn * bf_lo(us));
        float oH = bv.y + dn * (accH[n][lane] + dn * bf_hi(us));
        union { float2 f; double d; } cvt;
        cvt.f = make_float2(oL, oH);
        __builtin_nontemporal_store(cvt.d, (double*)(out + (size_t)gn * 128 + 2 * lane));
    }
}

extern "C" void kernel_launch(void* const* d_in, const int* in_sizes, int n_in,
                              void* d_out, int out_size, void* d_ws, size_t ws_size,
                              hipStream_t stream) {
    const float* x     = (const float*)d_in[0];
    const int*   eidx  = (const int*)d_in[1];   // [2,E] int32
    const float* eattr = (const float*)d_in[2];
    const float* W     = (const float*)d_in[3];
    const float* bias  = (const float*)d_in[4];
    int N = in_sizes[0] / 128;
    int E = in_sizes[2];
    const int* row = eidx;
    const int* col = eidx + E;

    int NC = (N + 63) >> 6;                        // 1563 buckets of 64 nodes
    int NBLK = (E + CHUNK - 1) / CHUNK;            // 391 hist/place blocks

    char* p = (char*)d_ws;
    auto carve = [&](size_t bytes) {
        char* q = p;
        p += (bytes + 255) & ~(size_t)255;
        return q;
    };
    unsigned short* h   = (unsigned short*)carve((size_t)N * 128 * sizeof(unsigned short));
    unsigned short* Wtg = (unsigned short*)carve(128 * 128 * sizeof(unsigned short));
    float* dis    = (float*)carve((size_t)N * sizeof(float));
    float* degf   = (float*)carve((size_t)N * sizeof(float));
    int*   histg  = (int*)carve((size_t)NC * NBLK * sizeof(int));
    int2*  srw    = (int2*)carve((size_t)E * sizeof(int2));
    int*   bsum   = (int*)carve(256 * sizeof(int));
    int*   boff   = (int*)carve(256 * sizeof(int));

    int M = NC * NBLK;
    int NBs = (M + ELEMS_PER_SCAN_BLOCK - 1) / ELEMS_PER_SCAN_BLOCK;  // 150 <= 256

    k_hist<<<NBLK, 256, 0, stream>>>(col, histg, degf, E, N, NC, NBLK);
    k_scan1<<<NBs, 256, 0, stream>>>(histg, histg, bsum, M);
    k_scan2<<<1, 256, 0, stream>>>(bsum, boff, NBs);
    k_scan3<<<NBs, 256, 0, stream>>>(histg, boff, M);
    k_place<<<NBLK, 256, 0, stream>>>(row, col, eattr, histg, srw, degf, E, NC, NBLK);
    k_dis<<<(N + 255) / 256, 256, 0, stream>>>(degf, dis, N);
    k_wprep<<<128, 128, 0, stream>>>(W, Wtg);
    k_gemm<<<(N + 63) / 64, 256, 0, stream>>>(x, Wtg, h, N);
    k_agg<<<NC, 256, 0, stream>>>(histg, (const long*)srw, (const unsigned int*)h,
                                  dis, bias, (float*)d_out, E, N, NC, NBLK);
}

// Round 3
// 312.789 us; speedup vs baseline: 4.5919x; 4.5919x over previous
//
#include <hip/hip_runtime.h>

// GCNConv: out = D^-1/2 (A+I) D^-1/2 X W + b
// N=100000, E=1600000, Din=Dout=128; x/W/b fp32, edge_index int32, out fp32.
//
// R7 = R4 (verified 274us) + masked unroll-16 gather.
//     R4: two-level counting sort (zero global atomics), packed payload
//     ((c&127)<<17 | row, w), bf16 h via MFMA GEMM, 1-wave-per-node gather.
//     R7 change: gather main loop widened 8->16 h-rows in flight with
//     index-clamp masking (kills the scalar tail). Latency-bound => more
//     MLP per wave. R5/R6 lesson: never trade away wave count / MLP.

#define ELEMS_PER_SCAN_BLOCK 2048  // 256 threads * 8
#define CHUNK 4096                 // edges per hist/place block

typedef __attribute__((ext_vector_type(8))) short short8;
typedef __attribute__((ext_vector_type(4))) float f32x4;

__device__ inline unsigned short f2bf(float f) {  // fp32 -> bf16 RNE
    unsigned u = __float_as_uint(f);
    u += 0x7fffu + ((u >> 16) & 1u);
    return (unsigned short)(u >> 16);
}
__device__ inline float bf_lo(unsigned u) { return __uint_as_float(u << 16); }
__device__ inline float bf_hi(unsigned u) { return __uint_as_float(u & 0xffff0000u); }

// ---- coarse histogram: LDS only ----
__global__ __launch_bounds__(256) void k_hist(const int* __restrict__ col,
                                              int* __restrict__ histg,
                                              int E, int NC, int NBLK) {
    __shared__ int lh[1024];
    int t = threadIdx.x, blk = blockIdx.x;
    for (int i = t; i < 1024; i += 256) lh[i] = 0;
    __syncthreads();
    int base = blk * CHUNK;
    #pragma unroll
    for (int i = 0; i < CHUNK / 256; ++i) {
        int e = base + i * 256 + t;
        if (e < E) atomicAdd(&lh[col[e] >> 7], 1);
    }
    __syncthreads();
    for (int b = t; b < NC; b += 256) histg[b * NBLK + blk] = lh[b];
}

// ---- scan (3 kernels) ----
__device__ inline int wave_incl_scan(int x, int lane) {
    #pragma unroll
    for (int d = 1; d < 64; d <<= 1) {
        int y = __shfl_up(x, d, 64);
        if (lane >= d) x += y;
    }
    return x;
}

__global__ void k_scan1(const int* __restrict__ in, int* __restrict__ out,
                        int* __restrict__ bsum, int M) {
    __shared__ int wsum[4];
    __shared__ int woff[4];
    int t = threadIdx.x, lane = t & 63, wid = t >> 6;
    int base = blockIdx.x * ELEMS_PER_SCAN_BLOCK + t * 8;
    int v[8];
    #pragma unroll
    for (int i = 0; i < 8; ++i) v[i] = (base + i < M) ? in[base + i] : 0;
    int run = 0;
    #pragma unroll
    for (int i = 0; i < 8; ++i) { int x = v[i]; v[i] = run; run += x; }
    int incl = wave_incl_scan(run, lane);
    int excl = incl - run;
    if (lane == 63) wsum[wid] = incl;
    __syncthreads();
    if (t == 0) {
        int r = 0;
        #pragma unroll
        for (int w = 0; w < 4; ++w) { int s = wsum[w]; woff[w] = r; r += s; }
        bsum[blockIdx.x] = r;
    }
    __syncthreads();
    int off = woff[wid] + excl;
    #pragma unroll
    for (int i = 0; i < 8; ++i)
        if (base + i < M) out[base + i] = v[i] + off;
}

__global__ void k_scan2(const int* __restrict__ bsum, int* __restrict__ boff, int NB) {
    __shared__ int wsum[4];
    __shared__ int woff[4];
    int t = threadIdx.x, lane = t & 63, wid = t >> 6;
    int x = (t < NB) ? bsum[t] : 0;
    int incl = wave_incl_scan(x, lane);
    int excl = incl - x;
    if (lane == 63) wsum[wid] = incl;
    __syncthreads();
    if (t == 0) {
        int r = 0;
        #pragma unroll
        for (int w = 0; w < 4; ++w) { int s = wsum[w]; woff[w] = r; r += s; }
    }
    __syncthreads();
    if (t < NB) boff[t] = woff[wid] + excl;
}

__global__ void k_scan3(int* __restrict__ arr, const int* __restrict__ boff, int M) {
    int t = threadIdx.x;
    int base = blockIdx.x * ELEMS_PER_SCAN_BLOCK + t * 8;
    int off = boff[blockIdx.x];
    #pragma unroll
    for (int i = 0; i < 8; ++i) {
        int idx = base + i;
        if (idx < M) arr[idx] += off;
    }
}

// ---- coarse placement: LDS cursors; payload ((c&127)<<17|row, w) ----
__global__ __launch_bounds__(256) void k_place(const int* __restrict__ row,
                                               const int* __restrict__ col,
                                               const float* __restrict__ wgt,
                                               const int* __restrict__ histg,
                                               int2* __restrict__ srw,
                                               int E, int NC, int NBLK) {
    __shared__ int lo[1024];
    int t = threadIdx.x, blk = blockIdx.x;
    for (int b = t; b < NC; b += 256) lo[b] = histg[b * NBLK + blk];
    __syncthreads();
    int base = blk * CHUNK;
    #pragma unroll
    for (int i = 0; i < CHUNK / 256; ++i) {
        int e = base + i * 256 + t;
        if (e < E) {
            int c = col[e];
            int pos = atomicAdd(&lo[c >> 7], 1);
            srw[pos] = make_int2(((c & 127) << 17) | row[e], __float_as_int(wgt[e]));
        }
    }
}

// ---- fine pass: exact CSR within each 128-node bucket + dis + spack ----
__global__ __launch_bounds__(256) void k_fine(const int* __restrict__ histg,
                                              const int2* __restrict__ srw,
                                              int* __restrict__ rowptr,
                                              float* __restrict__ dis,
                                              int2* __restrict__ spack,
                                              int E, int N, int NC, int NBLK) {
    __shared__ int cnt128[128];
    __shared__ float degf[128];
    __shared__ int cur128[128];
    __shared__ int wtot[2];
    int t = threadIdx.x, b = blockIdx.x;
    int nb = b << 7;
    int start = histg[b * NBLK];
    int end = (b == NC - 1) ? E : histg[(b + 1) * NBLK];
    if (t < 128) { cnt128[t] = 0; degf[t] = 1.0f; }  // 1.0 = self-loop weight
    __syncthreads();
    // phase 1: histogram + weighted degree
    for (int j = start + t; j < end; j += 256) {
        int2 s = srw[j];
        int c = s.x >> 17;
        atomicAdd(&cnt128[c], 1);
        atomicAdd(&degf[c], __int_as_float(s.y));
    }
    __syncthreads();
    // phase 2: 128-entry exclusive scan, write rowptr/dis, seed cursors
    int v = 0, incl = 0;
    if (t < 128) {
        v = cnt128[t];
        incl = wave_incl_scan(v, t & 63);
        if ((t & 63) == 63) wtot[t >> 6] = incl;
    }
    __syncthreads();
    if (t < 128) {
        int excl = incl - v + ((t >= 64) ? wtot[0] : 0);
        int p = start + excl;
        cur128[t] = p;
        int n = nb + t;
        if (n < N) {
            rowptr[n] = p;
            dis[n] = rsqrtf(degf[t]);
        }
    }
    if (t == 0 && b == NC - 1) rowptr[N] = E;
    __syncthreads();
    // phase 3: final placement (strip c bits -> (row, w))
    for (int j = start + t; j < end; j += 256) {
        int2 s = srw[j];
        int c = s.x >> 17;
        int pos = atomicAdd(&cur128[c], 1);
        spack[pos] = make_int2(s.x & 0x1FFFF, s.y);
    }
}

// ---- W transpose + bf16 convert ----
__global__ void k_wprep(const float* __restrict__ W, unsigned short* __restrict__ Wtg) {
    int n = blockIdx.x;
    int k = threadIdx.x;
    Wtg[n * 128 + k] = f2bf(W[k * 128 + n]);
}

// ---- h = x @ W, bf16 MFMA 16x16x32. 64 rows x 128 cols / block, 4 waves. ----
__global__ __launch_bounds__(256) void k_gemm(const float* __restrict__ x,
                                              const unsigned short* __restrict__ Wtg,
                                              unsigned short* __restrict__ h, int N) {
    __shared__ short Xs[64][136];
    __shared__ short Ws[128][136];
    int t = threadIdx.x;
    int lane = t & 63, wid = t >> 6;
    int row0 = blockIdx.x * 64;
    {
        int r = t >> 2;
        int kseg = (t & 3) * 32;
        int gr = row0 + r;
        const float4* src = (const float4*)(x + (size_t)gr * 128 + kseg);
        #pragma unroll
        for (int i = 0; i < 4; ++i) {
            float4 v0 = make_float4(0.f, 0.f, 0.f, 0.f), v1 = v0;
            if (gr < N) { v0 = src[2 * i]; v1 = src[2 * i + 1]; }
            short8 p;
            p[0] = (short)f2bf(v0.x); p[1] = (short)f2bf(v0.y);
            p[2] = (short)f2bf(v0.z); p[3] = (short)f2bf(v0.w);
            p[4] = (short)f2bf(v1.x); p[5] = (short)f2bf(v1.y);
            p[6] = (short)f2bf(v1.z); p[7] = (short)f2bf(v1.w);
            *(short8*)&Xs[r][kseg + 8 * i] = p;
        }
    }
    {
        int n = t >> 1;
        int seg = (t & 1) * 64;
        const short* wsrc = (const short*)Wtg + n * 128 + seg;
        #pragma unroll
        for (int i = 0; i < 8; ++i)
            *(short8*)&Ws[n][seg + 8 * i] = *(const short8*)(wsrc + 8 * i);
    }
    __syncthreads();

    int q = lane >> 4;
    int m = lane & 15;
    f32x4 acc[8];
    #pragma unroll
    for (int tde = 0; tde < 8; ++tde) acc[tde] = (f32x4){0.f, 0.f, 0.f, 0.f};
    #pragma unroll
    for (int kc = 0; kc < 128; kc += 32) {
        short8 af = *(const short8*)&Xs[wid * 16 + m][kc + q * 8];
        #pragma unroll
        for (int tde = 0; tde < 8; ++tde) {
            short8 bf = *(const short8*)&Ws[tde * 16 + m][kc + q * 8];
            acc[tde] = __builtin_amdgcn_mfma_f32_16x16x32_bf16(af, bf, acc[tde], 0, 0, 0);
        }
    }
    #pragma unroll
    for (int r = 0; r < 4; ++r) {
        int grow = row0 + wid * 16 + q * 4 + r;
        if (grow < N) {
            #pragma unroll
            for (int tde = 0; tde < 8; ++tde)
                h[(size_t)grow * 128 + tde * 16 + m] = f2bf(acc[tde][r]);
        }
    }
}

// ---- gather v5: 1 wave/node, masked unroll-16 (16 h-rows in flight),
//      no scalar tail, nt loads for spack, nt store for out ----
__global__ __launch_bounds__(256) void k_gather(const unsigned int* __restrict__ hb,
                                                const float* __restrict__ dis,
                                                const int* __restrict__ rowptr,
                                                const long* __restrict__ spackl,
                                                const float* __restrict__ bias,
                                                float* __restrict__ out, int N) {
    int gid = blockIdx.x * blockDim.x + threadIdx.x;
    int node = gid >> 6;
    int lane = gid & 63;
    if (node >= N) return;
    node = __builtin_amdgcn_readfirstlane(node);

    float dn = dis[node];
    unsigned u = hb[(size_t)node * 64 + lane];
    float2 acc;
    acc.x = dn * bf_lo(u);
    acc.y = dn * bf_hi(u);

    int jb = rowptr[node], je = rowptr[node + 1];
    int le = je - 1;
    for (int j = jb; j < je; j += 16) {  // 16 h-rows in flight, masked
        long q0  = __builtin_nontemporal_load(spackl + (j + 0  < je ? j + 0  : le));
        long q1  = __builtin_nontemporal_load(spackl + (j + 1  < je ? j + 1  : le));
        long q2  = __builtin_nontemporal_load(spackl + (j + 2  < je ? j + 2  : le));
        long q3  = __builtin_nontemporal_load(spackl + (j + 3  < je ? j + 3  : le));
        long q4  = __builtin_nontemporal_load(spackl + (j + 4  < je ? j + 4  : le));
        long q5  = __builtin_nontemporal_load(spackl + (j + 5  < je ? j + 5  : le));
        long q6  = __builtin_nontemporal_load(spackl + (j + 6  < je ? j + 6  : le));
        long q7  = __builtin_nontemporal_load(spackl + (j + 7  < je ? j + 7  : le));
        long q8  = __builtin_nontemporal_load(spackl + (j + 8  < je ? j + 8  : le));
        long q9  = __builtin_nontemporal_load(spackl + (j + 9  < je ? j + 9  : le));
        long q10 = __builtin_nontemporal_load(spackl + (j + 10 < je ? j + 10 : le));
        long q11 = __builtin_nontemporal_load(spackl + (j + 11 < je ? j + 11 : le));
        long q12 = __builtin_nontemporal_load(spackl + (j + 12 < je ? j + 12 : le));
        long q13 = __builtin_nontemporal_load(spackl + (j + 13 < je ? j + 13 : le));
        long q14 = __builtin_nontemporal_load(spackl + (j + 14 < je ? j + 14 : le));
        long q15 = __builtin_nontemporal_load(spackl + (j + 15 < je ? j + 15 : le));
        int r0  = __builtin_amdgcn_readfirstlane((int)q0);
        int r1  = __builtin_amdgcn_readfirstlane((int)q1);
        int r2  = __builtin_amdgcn_readfirstlane((int)q2);
        int r3  = __builtin_amdgcn_readfirstlane((int)q3);
        int r4  = __builtin_amdgcn_readfirstlane((int)q4);
        int r5  = __builtin_amdgcn_readfirstlane((int)q5);
        int r6  = __builtin_amdgcn_readfirstlane((int)q6);
        int r7  = __builtin_amdgcn_readfirstlane((int)q7);
        int r8  = __builtin_amdgcn_readfirstlane((int)q8);
        int r9  = __builtin_amdgcn_readfirstlane((int)q9);
        int r10 = __builtin_amdgcn_readfirstlane((int)q10);
        int r11 = __builtin_amdgcn_readfirstlane((int)q11);
        int r12 = __builtin_amdgcn_readfirstlane((int)q12);
        int r13 = __builtin_amdgcn_readfirstlane((int)q13);
        int r14 = __builtin_amdgcn_readfirstlane((int)q14);
        int r15 = __builtin_amdgcn_readfirstlane((int)q15);
        unsigned u0  = hb[(size_t)r0  * 64 + lane];
        unsigned u1  = hb[(size_t)r1  * 64 + lane];
        unsigned u2  = hb[(size_t)r2  * 64 + lane];
        unsigned u3  = hb[(size_t)r3  * 64 + lane];
        unsigned u4  = hb[(size_t)r4  * 64 + lane];
        unsigned u5  = hb[(size_t)r5  * 64 + lane];
        unsigned u6  = hb[(size_t)r6  * 64 + lane];
        unsigned u7  = hb[(size_t)r7  * 64 + lane];
        unsigned u8  = hb[(size_t)r8  * 64 + lane];
        unsigned u9  = hb[(size_t)r9  * 64 + lane];
        unsigned u10 = hb[(size_t)r10 * 64 + lane];
        unsigned u11 = hb[(size_t)r11 * 64 + lane];
        unsigned u12 = hb[(size_t)r12 * 64 + lane];
        unsigned u13 = hb[(size_t)r13 * 64 + lane];
        unsigned u14 = hb[(size_t)r14 * 64 + lane];
        unsigned u15 = hb[(size_t)r15 * 64 + lane];
        float a0  = (j + 0  < je) ? dis[r0]  * __uint_as_float((unsigned)(q0  >> 32)) : 0.f;
        float a1  = (j + 1  < je) ? dis[r1]  * __uint_as_float((unsigned)(q1  >> 32)) : 0.f;
        float a2  = (j + 2  < je) ? dis[r2]  * __uint_as_float((unsigned)(q2  >> 32)) : 0.f;
        float a3  = (j + 3  < je) ? dis[r3]  * __uint_as_float((unsigned)(q3  >> 32)) : 0.f;
        float a4  = (j + 4  < je) ? dis[r4]  * __uint_as_float((unsigned)(q4  >> 32)) : 0.f;
        float a5  = (j + 5  < je) ? dis[r5]  * __uint_as_float((unsigned)(q5  >> 32)) : 0.f;
        float a6  = (j + 6  < je) ? dis[r6]  * __uint_as_float((unsigned)(q6  >> 32)) : 0.f;
        float a7  = (j + 7  < je) ? dis[r7]  * __uint_as_float((unsigned)(q7  >> 32)) : 0.f;
        float a8  = (j + 8  < je) ? dis[r8]  * __uint_as_float((unsigned)(q8  >> 32)) : 0.f;
        float a9  = (j + 9  < je) ? dis[r9]  * __uint_as_float((unsigned)(q9  >> 32)) : 0.f;
        float a10 = (j + 10 < je) ? dis[r10] * __uint_as_float((unsigned)(q10 >> 32)) : 0.f;
        float a11 = (j + 11 < je) ? dis[r11] * __uint_as_float((unsigned)(q11 >> 32)) : 0.f;
        float a12 = (j + 12 < je) ? dis[r12] * __uint_as_float((unsigned)(q12 >> 32)) : 0.f;
        float a13 = (j + 13 < je) ? dis[r13] * __uint_as_float((unsigned)(q13 >> 32)) : 0.f;
        float a14 = (j + 14 < je) ? dis[r14] * __uint_as_float((unsigned)(q14 >> 32)) : 0.f;
        float a15 = (j + 15 < je) ? dis[r15] * __uint_as_float((unsigned)(q15 >> 32)) : 0.f;
        acc.x = fmaf(a0,  bf_lo(u0),  acc.x); acc.y = fmaf(a0,  bf_hi(u0),  acc.y);
        acc.x = fmaf(a1,  bf_lo(u1),  acc.x); acc.y = fmaf(a1,  bf_hi(u1),  acc.y);
        acc.x = fmaf(a2,  bf_lo(u2),  acc.x); acc.y = fmaf(a2,  bf_hi(u2),  acc.y);
        acc.x = fmaf(a3,  bf_lo(u3),  acc.x); acc.y = fmaf(a3,  bf_hi(u3),  acc.y);
        acc.x = fmaf(a4,  bf_lo(u4),  acc.x); acc.y = fmaf(a4,  bf_hi(u4),  acc.y);
        acc.x = fmaf(a5,  bf_lo(u5),  acc.x); acc.y = fmaf(a5,  bf_hi(u5),  acc.y);
        acc.x = fmaf(a6,  bf_lo(u6),  acc.x); acc.y = fmaf(a6,  bf_hi(u6),  acc.y);
        acc.x = fmaf(a7,  bf_lo(u7),  acc.x); acc.y = fmaf(a7,  bf_hi(u7),  acc.y);
        acc.x = fmaf(a8,  bf_lo(u8),  acc.x); acc.y = fmaf(a8,  bf_hi(u8),  acc.y);
        acc.x = fmaf(a9,  bf_lo(u9),  acc.x); acc.y = fmaf(a9,  bf_hi(u9),  acc.y);
        acc.x = fmaf(a10, bf_lo(u10), acc.x); acc.y = fmaf(a10, bf_hi(u10), acc.y);
        acc.x = fmaf(a11, bf_lo(u11), acc.x); acc.y = fmaf(a11, bf_hi(u11), acc.y);
        acc.x = fmaf(a12, bf_lo(u12), acc.x); acc.y = fmaf(a12, bf_hi(u12), acc.y);
        acc.x = fmaf(a13, bf_lo(u13), acc.x); acc.y = fmaf(a13, bf_hi(u13), acc.y);
        acc.x = fmaf(a14, bf_lo(u14), acc.x); acc.y = fmaf(a14, bf_hi(u14), acc.y);
        acc.x = fmaf(a15, bf_lo(u15), acc.x); acc.y = fmaf(a15, bf_hi(u15), acc.y);
    }

    int c0 = lane * 2;
    float2 bv = *(const float2*)(bias + c0);
    float2 o;
    o.x = bv.x + dn * acc.x;
    o.y = bv.y + dn * acc.y;
    union { float2 f; double d; } cvt;
    cvt.f = o;
    __builtin_nontemporal_store(cvt.d, (double*)(out + (size_t)node * 128 + c0));
}

extern "C" void kernel_launch(void* const* d_in, const int* in_sizes, int n_in,
                              void* d_out, int out_size, void* d_ws, size_t ws_size,
                              hipStream_t stream) {
    const float* x     = (const float*)d_in[0];
    const int*   eidx  = (const int*)d_in[1];   // [2,E] int32
    const float* eattr = (const float*)d_in[2];
    const float* W     = (const float*)d_in[3];
    const float* bias  = (const float*)d_in[4];
    int N = in_sizes[0] / 128;
    int E = in_sizes[2];
    const int* row = eidx;
    const int* col = eidx + E;

    int NC = (N + 127) >> 7;                       // 782 coarse buckets
    int NBLK = (E + CHUNK - 1) / CHUNK;            // 391 hist/place blocks

    char* p = (char*)d_ws;
    auto carve = [&](size_t bytes) {
        char* q = p;
        p += (bytes + 255) & ~(size_t)255;
        return q;
    };
    unsigned short* h   = (unsigned short*)carve((size_t)N * 128 * sizeof(unsigned short));
    unsigned short* Wtg = (unsigned short*)carve(128 * 128 * sizeof(unsigned short));
    float* dis    = (float*)carve((size_t)N * sizeof(float));
    int*   rowptr = (int*)carve((size_t)(N + 1) * sizeof(int));
    int*   histg  = (int*)carve((size_t)NC * NBLK * sizeof(int));
    int2*  srw    = (int2*)carve((size_t)E * sizeof(int2));
    int2*  spack  = (int2*)carve((size_t)E * sizeof(int2));
    int*   bsum   = (int*)carve(256 * sizeof(int));
    int*   boff   = (int*)carve(256 * sizeof(int));

    int M = NC * NBLK;
    int NBs = (M + ELEMS_PER_SCAN_BLOCK - 1) / ELEMS_PER_SCAN_BLOCK;

    k_hist<<<NBLK, 256, 0, stream>>>(col, histg, E, NC, NBLK);
    k_scan1<<<NBs, 256, 0, stream>>>(histg, histg, bsum, M);
    k_scan2<<<1, 256, 0, stream>>>(bsum, boff, NBs);
    k_scan3<<<NBs, 256, 0, stream>>>(histg, boff, M);
    k_place<<<NBLK, 256, 0, stream>>>(row, col, eattr, histg, srw, E, NC, NBLK);
    k_fine<<<NC, 256, 0, stream>>>(histg, srw, rowptr, dis, spack, E, N, NC, NBLK);
    k_wprep<<<128, 128, 0, stream>>>(W, Wtg);
    k_gemm<<<(N + 63) / 64, 256, 0, stream>>>(x, Wtg, h, N);
    {
        size_t threads = (size_t)N * 64;
        int blocks = (int)((threads + 255) / 256);
        k_gather<<<blocks, 256, 0, stream>>>((const unsigned int*)h, dis, rowptr,
                                             (const long*)spack, bias, (float*)d_out, N);
    }
}

// Round 4
// 270.168 us; speedup vs baseline: 5.3163x; 1.1578x over previous
//
#include <hip/hip_runtime.h>

// GCNConv: out = D^-1/2 (A+I) D^-1/2 X W + b
// N=100000, E=1600000, Din=Dout=128; x/W/b fp32, edge_index int32, out fp32.
//
// R8 = R4 structure (verified 274us; gather 73.6us) with two targeted fixes:
//  1. k_gather: unroll-8 + scalar tail (R4, proven) + explicit software
//     prefetch of next iteration's 8 spack longs BEFORE the fmaf wait —
//     hides the per-8-edge spack line round-trip. (R7 lesson: cost ∝
//     issued gather-load count; never widen with masked loads.)
//  2. k_place: LDS-staged bucket-sorted output. Old version scattered 8B
//     writes across ~64 lines per wave store (~100MB line-RMW). New: count
//     -> block scan -> LDS scatter -> write out in bucket order (mostly
//     consecutive addresses, ~5x fewer line touches). CHUNK=2048.

#define ELEMS_PER_SCAN_BLOCK 4096  // 256 threads * 16
#define CHUNK 2048                 // edges per hist/place block

typedef __attribute__((ext_vector_type(8))) short short8;
typedef __attribute__((ext_vector_type(4))) float f32x4;

__device__ inline unsigned short f2bf(float f) {  // fp32 -> bf16 RNE
    unsigned u = __float_as_uint(f);
    u += 0x7fffu + ((u >> 16) & 1u);
    return (unsigned short)(u >> 16);
}
__device__ inline float bf_lo(unsigned u) { return __uint_as_float(u << 16); }
__device__ inline float bf_hi(unsigned u) { return __uint_as_float(u & 0xffff0000u); }

// ---- coarse histogram: LDS only ----
__global__ __launch_bounds__(256) void k_hist(const int* __restrict__ col,
                                              int* __restrict__ histg,
                                              int E, int NC, int NBLK) {
    __shared__ int lh[1024];
    int t = threadIdx.x, blk = blockIdx.x;
    for (int i = t; i < 1024; i += 256) lh[i] = 0;
    __syncthreads();
    int base = blk * CHUNK;
    #pragma unroll
    for (int i = 0; i < CHUNK / 256; ++i) {
        int e = base + i * 256 + t;
        if (e < E) atomicAdd(&lh[col[e] >> 7], 1);
    }
    __syncthreads();
    for (int b = t; b < NC; b += 256) histg[b * NBLK + blk] = lh[b];
}

// ---- scan (3 kernels) ----
__device__ inline int wave_incl_scan(int x, int lane) {
    #pragma unroll
    for (int d = 1; d < 64; d <<= 1) {
        int y = __shfl_up(x, d, 64);
        if (lane >= d) x += y;
    }
    return x;
}

__global__ void k_scan1(const int* __restrict__ in, int* __restrict__ out,
                        int* __restrict__ bsum, int M) {
    __shared__ int wsum[4];
    __shared__ int woff[4];
    int t = threadIdx.x, lane = t & 63, wid = t >> 6;
    int base = blockIdx.x * ELEMS_PER_SCAN_BLOCK + t * 16;
    int v[16];
    #pragma unroll
    for (int i = 0; i < 16; ++i) v[i] = (base + i < M) ? in[base + i] : 0;
    int run = 0;
    #pragma unroll
    for (int i = 0; i < 16; ++i) { int x = v[i]; v[i] = run; run += x; }
    int incl = wave_incl_scan(run, lane);
    int excl = incl - run;
    if (lane == 63) wsum[wid] = incl;
    __syncthreads();
    if (t == 0) {
        int r = 0;
        #pragma unroll
        for (int w = 0; w < 4; ++w) { int s = wsum[w]; woff[w] = r; r += s; }
        bsum[blockIdx.x] = r;
    }
    __syncthreads();
    int off = woff[wid] + excl;
    #pragma unroll
    for (int i = 0; i < 16; ++i)
        if (base + i < M) out[base + i] = v[i] + off;
}

__global__ void k_scan2(const int* __restrict__ bsum, int* __restrict__ boff, int NB) {
    __shared__ int wsum[4];
    __shared__ int woff[4];
    int t = threadIdx.x, lane = t & 63, wid = t >> 6;
    int x = (t < NB) ? bsum[t] : 0;
    int incl = wave_incl_scan(x, lane);
    int excl = incl - x;
    if (lane == 63) wsum[wid] = incl;
    __syncthreads();
    if (t == 0) {
        int r = 0;
        #pragma unroll
        for (int w = 0; w < 4; ++w) { int s = wsum[w]; woff[w] = r; r += s; }
    }
    __syncthreads();
    if (t < NB) boff[t] = woff[wid] + excl;
}

__global__ void k_scan3(int* __restrict__ arr, const int* __restrict__ boff, int M) {
    int t = threadIdx.x;
    int base = blockIdx.x * ELEMS_PER_SCAN_BLOCK + t * 16;
    int off = boff[blockIdx.x];
    #pragma unroll
    for (int i = 0; i < 16; ++i) {
        int idx = base + i;
        if (idx < M) arr[idx] += off;
    }
}

// ---- placement: LDS-staged, bucket-sorted coalesced output ----
__global__ __launch_bounds__(256) void k_place(const int* __restrict__ row,
                                               const int* __restrict__ col,
                                               const float* __restrict__ wgt,
                                               const int* __restrict__ histg,
                                               int2* __restrict__ srw,
                                               int E, int NC, int NBLK) {
    __shared__ int lcnt[1024];      // counts -> cursors (local slot)
    __shared__ int gadj[1024];      // global_base - local_base per bucket
    __shared__ int2 stage[CHUNK];   // 16 KB payload staged by local slot
    __shared__ int sdst[CHUNK];     // 8 KB global dest per slot
    __shared__ int wsum[4];
    __shared__ int woff[4];
    int t = threadIdx.x, blk = blockIdx.x;
    int lane = t & 63, wid = t >> 6;
    int base = blk * CHUNK;
    int nE = min(CHUNK, E - base);
    for (int b = t; b < 1024; b += 256) lcnt[b] = 0;
    __syncthreads();
    // pass A: local count
    #pragma unroll
    for (int i = 0; i < CHUNK / 256; ++i) {
        int e = base + i * 256 + t;
        if (e < E) atomicAdd(&lcnt[col[e] >> 7], 1);
    }
    __syncthreads();
    // block-wide exclusive scan of lcnt[0..1024), 4 entries/thread
    int c4[4];
    int sum = 0;
    #pragma unroll
    for (int i = 0; i < 4; ++i) { int v = lcnt[t * 4 + i]; c4[i] = sum; sum += v; }
    int incl = wave_incl_scan(sum, lane);
    int excl = incl - sum;
    if (lane == 63) wsum[wid] = incl;
    __syncthreads();
    if (t == 0) {
        int r = 0;
        #pragma unroll
        for (int w = 0; w < 4; ++w) { int s = wsum[w]; woff[w] = r; r += s; }
    }
    __syncthreads();
    int tb = woff[wid] + excl;
    // rewrite lcnt as local cursors; gadj = global_base - local_base
    #pragma unroll
    for (int i = 0; i < 4; ++i) {
        int idx = t * 4 + i;
        int b0 = tb + c4[i];
        int gb = (idx < NC) ? histg[idx * NBLK + blk] : 0;
        gadj[idx] = gb - b0;
        lcnt[idx] = b0;
    }
    __syncthreads();
    // pass B: scatter into LDS by bucket
    #pragma unroll
    for (int i = 0; i < CHUNK / 256; ++i) {
        int e = base + i * 256 + t;
        if (e < E) {
            int c = col[e];
            int slot = atomicAdd(&lcnt[c >> 7], 1);
            stage[slot] = make_int2(((c & 127) << 17) | row[e], __float_as_int(wgt[e]));
            sdst[slot] = gadj[c >> 7] + slot;
        }
    }
    __syncthreads();
    // output: consecutive slots -> mostly-consecutive global dests
    for (int s_ = t; s_ < nE; s_ += 256) {
        srw[sdst[s_]] = stage[s_];
    }
}

// ---- fine pass: exact CSR within each 128-node bucket + dis + spack ----
__global__ __launch_bounds__(256) void k_fine(const int* __restrict__ histg,
                                              const int2* __restrict__ srw,
                                              int* __restrict__ rowptr,
                                              float* __restrict__ dis,
                                              int2* __restrict__ spack,
                                              int E, int N, int NC, int NBLK) {
    __shared__ int cnt128[128];
    __shared__ float degf[128];
    __shared__ int cur128[128];
    __shared__ int wtot[2];
    int t = threadIdx.x, b = blockIdx.x;
    int nb = b << 7;
    int start = histg[b * NBLK];
    int end = (b == NC - 1) ? E : histg[(b + 1) * NBLK];
    if (t < 128) { cnt128[t] = 0; degf[t] = 1.0f; }  // 1.0 = self-loop weight
    __syncthreads();
    // phase 1: histogram + weighted degree
    for (int j = start + t; j < end; j += 256) {
        int2 s = srw[j];
        int c = s.x >> 17;
        atomicAdd(&cnt128[c], 1);
        atomicAdd(&degf[c], __int_as_float(s.y));
    }
    __syncthreads();
    // phase 2: 128-entry exclusive scan, write rowptr/dis, seed cursors
    int v = 0, incl = 0;
    if (t < 128) {
        v = cnt128[t];
        incl = wave_incl_scan(v, t & 63);
        if ((t & 63) == 63) wtot[t >> 6] = incl;
    }
    __syncthreads();
    if (t < 128) {
        int excl = incl - v + ((t >= 64) ? wtot[0] : 0);
        int p = start + excl;
        cur128[t] = p;
        int n = nb + t;
        if (n < N) {
            rowptr[n] = p;
            dis[n] = rsqrtf(degf[t]);
        }
    }
    if (t == 0 && b == NC - 1) rowptr[N] = E;
    __syncthreads();
    // phase 3: final placement (strip c bits -> (row, w))
    for (int j = start + t; j < end; j += 256) {
        int2 s = srw[j];
        int c = s.x >> 17;
        int pos = atomicAdd(&cur128[c], 1);
        spack[pos] = make_int2(s.x & 0x1FFFF, s.y);
    }
}

// ---- W transpose + bf16 convert ----
__global__ void k_wprep(const float* __restrict__ W, unsigned short* __restrict__ Wtg) {
    int n = blockIdx.x;
    int k = threadIdx.x;
    Wtg[n * 128 + k] = f2bf(W[k * 128 + n]);
}

// ---- h = x @ W, bf16 MFMA 16x16x32. 64 rows x 128 cols / block, 4 waves. ----
__global__ __launch_bounds__(256) void k_gemm(const float* __restrict__ x,
                                              const unsigned short* __restrict__ Wtg,
                                              unsigned short* __restrict__ h, int N) {
    __shared__ short Xs[64][136];
    __shared__ short Ws[128][136];
    int t = threadIdx.x;
    int lane = t & 63, wid = t >> 6;
    int row0 = blockIdx.x * 64;
    {
        int r = t >> 2;
        int kseg = (t & 3) * 32;
        int gr = row0 + r;
        const float4* src = (const float4*)(x + (size_t)gr * 128 + kseg);
        #pragma unroll
        for (int i = 0; i < 4; ++i) {
            float4 v0 = make_float4(0.f, 0.f, 0.f, 0.f), v1 = v0;
            if (gr < N) { v0 = src[2 * i]; v1 = src[2 * i + 1]; }
            short8 p;
            p[0] = (short)f2bf(v0.x); p[1] = (short)f2bf(v0.y);
            p[2] = (short)f2bf(v0.z); p[3] = (short)f2bf(v0.w);
            p[4] = (short)f2bf(v1.x); p[5] = (short)f2bf(v1.y);
            p[6] = (short)f2bf(v1.z); p[7] = (short)f2bf(v1.w);
            *(short8*)&Xs[r][kseg + 8 * i] = p;
        }
    }
    {
        int n = t >> 1;
        int seg = (t & 1) * 64;
        const short* wsrc = (const short*)Wtg + n * 128 + seg;
        #pragma unroll
        for (int i = 0; i < 8; ++i)
            *(short8*)&Ws[n][seg + 8 * i] = *(const short8*)(wsrc + 8 * i);
    }
    __syncthreads();

    int q = lane >> 4;
    int m = lane & 15;
    f32x4 acc[8];
    #pragma unroll
    for (int tde = 0; tde < 8; ++tde) acc[tde] = (f32x4){0.f, 0.f, 0.f, 0.f};
    #pragma unroll
    for (int kc = 0; kc < 128; kc += 32) {
        short8 af = *(const short8*)&Xs[wid * 16 + m][kc + q * 8];
        #pragma unroll
        for (int tde = 0; tde < 8; ++tde) {
            short8 bf = *(const short8*)&Ws[tde * 16 + m][kc + q * 8];
            acc[tde] = __builtin_amdgcn_mfma_f32_16x16x32_bf16(af, bf, acc[tde], 0, 0, 0);
        }
    }
    #pragma unroll
    for (int r = 0; r < 4; ++r) {
        int grow = row0 + wid * 16 + q * 4 + r;
        if (grow < N) {
            #pragma unroll
            for (int tde = 0; tde < 8; ++tde)
                h[(size_t)grow * 128 + tde * 16 + m] = f2bf(acc[tde][r]);
        }
    }
}

// ---- gather v6: R4 unroll-8 + scalar tail, with software-pipelined spack
//      prefetch (next 8 longs issue before the fmaf vmcnt wait) ----
__global__ __launch_bounds__(256) void k_gather(const unsigned int* __restrict__ hb,
                                                const float* __restrict__ dis,
                                                const int* __restrict__ rowptr,
                                                const long* __restrict__ spackl,
                                                const float* __restrict__ bias,
                                                float* __restrict__ out, int N) {
    int gid = blockIdx.x * blockDim.x + threadIdx.x;
    int node = gid >> 6;
    int lane = gid & 63;
    if (node >= N) return;
    node = __builtin_amdgcn_readfirstlane(node);

    float dn = dis[node];
    unsigned u = hb[(size_t)node * 64 + lane];
    float2 acc;
    acc.x = dn * bf_lo(u);
    acc.y = dn * bf_hi(u);

    int jb = rowptr[node], je = rowptr[node + 1];
    int j = jb;
    long q0, q1, q2, q3, q4, q5, q6, q7;
    if (j + 8 <= je) {
        q0 = __builtin_nontemporal_load(spackl + j);
        q1 = __builtin_nontemporal_load(spackl + j + 1);
        q2 = __builtin_nontemporal_load(spackl + j + 2);
        q3 = __builtin_nontemporal_load(spackl + j + 3);
        q4 = __builtin_nontemporal_load(spackl + j + 4);
        q5 = __builtin_nontemporal_load(spackl + j + 5);
        q6 = __builtin_nontemporal_load(spackl + j + 6);
        q7 = __builtin_nontemporal_load(spackl + j + 7);
    }
    for (; j + 8 <= je; j += 8) {
        int r0 = __builtin_amdgcn_readfirstlane((int)q0);
        int r1 = __builtin_amdgcn_readfirstlane((int)q1);
        int r2 = __builtin_amdgcn_readfirstlane((int)q2);
        int r3 = __builtin_amdgcn_readfirstlane((int)q3);
        int r4 = __builtin_amdgcn_readfirstlane((int)q4);
        int r5 = __builtin_amdgcn_readfirstlane((int)q5);
        int r6 = __builtin_amdgcn_readfirstlane((int)q6);
        int r7 = __builtin_amdgcn_readfirstlane((int)q7);
        // issue 8 h-row loads (the expensive random gathers)
        unsigned u0 = hb[(size_t)r0 * 64 + lane];
        unsigned u1 = hb[(size_t)r1 * 64 + lane];
        unsigned u2 = hb[(size_t)r2 * 64 + lane];
        unsigned u3 = hb[(size_t)r3 * 64 + lane];
        unsigned u4 = hb[(size_t)r4 * 64 + lane];
        unsigned u5 = hb[(size_t)r5 * 64 + lane];
        unsigned u6 = hb[(size_t)r6 * 64 + lane];
        unsigned u7 = hb[(size_t)r7 * 64 + lane];
        // prefetch next iteration's spack longs (or reload current line)
        int jn = (j + 16 <= je) ? j + 8 : j;
        long n0 = __builtin_nontemporal_load(spackl + jn);
        long n1 = __builtin_nontemporal_load(spackl + jn + 1);
        long n2 = __builtin_nontemporal_load(spackl + jn + 2);
        long n3 = __builtin_nontemporal_load(spackl + jn + 3);
        long n4 = __builtin_nontemporal_load(spackl + jn + 4);
        long n5 = __builtin_nontemporal_load(spackl + jn + 5);
        long n6 = __builtin_nontemporal_load(spackl + jn + 6);
        long n7 = __builtin_nontemporal_load(spackl + jn + 7);
        float a0 = dis[r0] * __uint_as_float((unsigned)((unsigned long)q0 >> 32));
        float a1 = dis[r1] * __uint_as_float((unsigned)((unsigned long)q1 >> 32));
        float a2 = dis[r2] * __uint_as_float((unsigned)((unsigned long)q2 >> 32));
        float a3 = dis[r3] * __uint_as_float((unsigned)((unsigned long)q3 >> 32));
        float a4 = dis[r4] * __uint_as_float((unsigned)((unsigned long)q4 >> 32));
        float a5 = dis[r5] * __uint_as_float((unsigned)((unsigned long)q5 >> 32));
        float a6 = dis[r6] * __uint_as_float((unsigned)((unsigned long)q6 >> 32));
        float a7 = dis[r7] * __uint_as_float((unsigned)((unsigned long)q7 >> 32));
        acc.x = fmaf(a0, bf_lo(u0), acc.x); acc.y = fmaf(a0, bf_hi(u0), acc.y);
        acc.x = fmaf(a1, bf_lo(u1), acc.x); acc.y = fmaf(a1, bf_hi(u1), acc.y);
        acc.x = fmaf(a2, bf_lo(u2), acc.x); acc.y = fmaf(a2, bf_hi(u2), acc.y);
        acc.x = fmaf(a3, bf_lo(u3), acc.x); acc.y = fmaf(a3, bf_hi(u3), acc.y);
        acc.x = fmaf(a4, bf_lo(u4), acc.x); acc.y = fmaf(a4, bf_hi(u4), acc.y);
        acc.x = fmaf(a5, bf_lo(u5), acc.x); acc.y = fmaf(a5, bf_hi(u5), acc.y);
        acc.x = fmaf(a6, bf_lo(u6), acc.x); acc.y = fmaf(a6, bf_hi(u6), acc.y);
        acc.x = fmaf(a7, bf_lo(u7), acc.x); acc.y = fmaf(a7, bf_hi(u7), acc.y);
        q0 = n0; q1 = n1; q2 = n2; q3 = n3; q4 = n4; q5 = n5; q6 = n6; q7 = n7;
    }
    for (; j < je; ++j) {
        long q = __builtin_nontemporal_load(spackl + j);
        int r = __builtin_amdgcn_readfirstlane((int)q);
        unsigned uu = hb[(size_t)r * 64 + lane];
        float a = dis[r] * __uint_as_float((unsigned)((unsigned long)q >> 32));
        acc.x = fmaf(a, bf_lo(uu), acc.x);
        acc.y = fmaf(a, bf_hi(uu), acc.y);
    }

    int c0 = lane * 2;
    float2 bv = *(const float2*)(bias + c0);
    float2 o;
    o.x = bv.x + dn * acc.x;
    o.y = bv.y + dn * acc.y;
    union { float2 f; double d; } cvt;
    cvt.f = o;
    __builtin_nontemporal_store(cvt.d, (double*)(out + (size_t)node * 128 + c0));
}

extern "C" void kernel_launch(void* const* d_in, const int* in_sizes, int n_in,
                              void* d_out, int out_size, void* d_ws, size_t ws_size,
                              hipStream_t stream) {
    const float* x     = (const float*)d_in[0];
    const int*   eidx  = (const int*)d_in[1];   // [2,E] int32
    const float* eattr = (const float*)d_in[2];
    const float* W     = (const float*)d_in[3];
    const float* bias  = (const float*)d_in[4];
    int N = in_sizes[0] / 128;
    int E = in_sizes[2];
    const int* row = eidx;
    const int* col = eidx + E;

    int NC = (N + 127) >> 7;                       // 782 coarse buckets
    int NBLK = (E + CHUNK - 1) / CHUNK;            // 782 hist/place blocks

    char* p = (char*)d_ws;
    auto carve = [&](size_t bytes) {
        char* q = p;
        p += (bytes + 255) & ~(size_t)255;
        return q;
    };
    unsigned short* h   = (unsigned short*)carve((size_t)N * 128 * sizeof(unsigned short));
    unsigned short* Wtg = (unsigned short*)carve(128 * 128 * sizeof(unsigned short));
    float* dis    = (float*)carve((size_t)N * sizeof(float));
    int*   rowptr = (int*)carve((size_t)(N + 1) * sizeof(int));
    int*   histg  = (int*)carve((size_t)NC * NBLK * sizeof(int));
    int2*  srw    = (int2*)carve((size_t)E * sizeof(int2));
    int2*  spack  = (int2*)carve((size_t)E * sizeof(int2));
    int*   bsum   = (int*)carve(256 * sizeof(int));
    int*   boff   = (int*)carve(256 * sizeof(int));

    int M = NC * NBLK;
    int NBs = (M + ELEMS_PER_SCAN_BLOCK - 1) / ELEMS_PER_SCAN_BLOCK;  // 150 <= 256

    k_hist<<<NBLK, 256, 0, stream>>>(col, histg, E, NC, NBLK);
    k_scan1<<<NBs, 256, 0, stream>>>(histg, histg, bsum, M);
    k_scan2<<<1, 256, 0, stream>>>(bsum, boff, NBs);
    k_scan3<<<NBs, 256, 0, stream>>>(histg, boff, M);
    k_place<<<NBLK, 256, 0, stream>>>(row, col, eattr, histg, srw, E, NC, NBLK);
    k_fine<<<NC, 256, 0, stream>>>(histg, srw, rowptr, dis, spack, E, N, NC, NBLK);
    k_wprep<<<128, 128, 0, stream>>>(W, Wtg);
    k_gemm<<<(N + 63) / 64, 256, 0, stream>>>(x, Wtg, h, N);
    {
        size_t threads = (size_t)N * 64;
        int blocks = (int)((threads + 255) / 256);
        k_gather<<<blocks, 256, 0, stream>>>((const unsigned int*)h, dis, rowptr,
                                             (const long*)spack, bias, (float*)d_out, N);
    }
}

// Round 5
// 260.978 us; speedup vs baseline: 5.5035x; 1.0352x over previous
//
#include <hip/hip_runtime.h>

// GCNConv: out = D^-1/2 (A+I) D^-1/2 X W + b
// N=100000, E=1600000, Din=Dout=128; x/W/b fp32, edge_index int32, out fp32.
//
// R9 = R8 dataflow (270us) restructured to 6 dispatches:
//   1. k_hist   (+ W-prep folded into blocks 0..63)
//   2. k_scan1
//   3. k_scan2  (k_scan3 deleted: consumers add boff[g>>12] on the fly)
//   4. k_pg     = k_place  + gemm blocks [0, GB1)      (block-range split)
//   5. k_fg     = k_fine(LDS-staged srw) + gemm blocks [GB1, GB)
//   6. k_gather (identical to R8's 74us version)
// Rationale: 270 - 74 = 196us spread over 8 small dispatches whose ideal
// traffic is ~30us of HBM => serial launch/drain bubbles + no overlap of
// the independent sort and GEMM chains. Fusing gemm under place/fine
// overlaps ~25us; scan3-fold and wprep-fold remove 3 launches.

#define ELEMS_PER_SCAN_BLOCK 4096  // 256 threads * 16
#define SCAN_SHIFT 12
#define CHUNK 2048                 // edges per hist/place block

typedef __attribute__((ext_vector_type(8))) short short8;
typedef __attribute__((ext_vector_type(4))) float f32x4;

__device__ inline unsigned short f2bf(float f) {  // fp32 -> bf16 RNE
    unsigned u = __float_as_uint(f);
    u += 0x7fffu + ((u >> 16) & 1u);
    return (unsigned short)(u >> 16);
}
__device__ inline float bf_lo(unsigned u) { return __uint_as_float(u << 16); }
__device__ inline float bf_hi(unsigned u) { return __uint_as_float(u & 0xffff0000u); }

// shared-memory union for the fused kernels (max 52.3 KB -> 3 blocks/CU)
union SmemU {
    struct { short Xs[64][136]; short Ws[128][136]; } g;                     // gemm
    struct { int lcnt[1024]; int gadj[1024]; int2 stage[CHUNK]; int sdst[CHUNK];
             int wsum[4]; int woff[4]; } p;                                  // place
    struct { int2 sbuf[3072]; int cnt128[128]; float degf[128]; int cur128[128];
             int wtot[2]; } f;                                               // fine
};

// ---- coarse histogram + W-prep fold ----
__global__ __launch_bounds__(256) void k_hist(const int* __restrict__ col,
                                              const float* __restrict__ W,
                                              int* __restrict__ histg,
                                              unsigned short* __restrict__ Wtg,
                                              int E, int NC, int NBLK) {
    __shared__ int lh[1024];
    int t = threadIdx.x, blk = blockIdx.x;
    if (blk < 64) {  // W transpose+bf16: 2 rows per block
        int n = blk * 2 + (t >> 7);
        int k = t & 127;
        Wtg[n * 128 + k] = f2bf(W[k * 128 + n]);
    }
    for (int i = t; i < 1024; i += 256) lh[i] = 0;
    __syncthreads();
    int base = blk * CHUNK;
    #pragma unroll
    for (int i = 0; i < CHUNK / 256; ++i) {
        int e = base + i * 256 + t;
        if (e < E) atomicAdd(&lh[col[e] >> 7], 1);
    }
    __syncthreads();
    for (int b = t; b < NC; b += 256) histg[b * NBLK + blk] = lh[b];
}

// ---- scan (2 kernels; block-offset applied by consumers) ----
__device__ inline int wave_incl_scan(int x, int lane) {
    #pragma unroll
    for (int d = 1; d < 64; d <<= 1) {
        int y = __shfl_up(x, d, 64);
        if (lane >= d) x += y;
    }
    return x;
}

__global__ void k_scan1(const int* __restrict__ in, int* __restrict__ out,
                        int* __restrict__ bsum, int M) {
    __shared__ int wsum[4];
    __shared__ int woff[4];
    int t = threadIdx.x, lane = t & 63, wid = t >> 6;
    int base = blockIdx.x * ELEMS_PER_SCAN_BLOCK + t * 16;
    int v[16];
    #pragma unroll
    for (int i = 0; i < 16; ++i) v[i] = (base + i < M) ? in[base + i] : 0;
    int run = 0;
    #pragma unroll
    for (int i = 0; i < 16; ++i) { int x = v[i]; v[i] = run; run += x; }
    int incl = wave_incl_scan(run, lane);
    int excl = incl - run;
    if (lane == 63) wsum[wid] = incl;
    __syncthreads();
    if (t == 0) {
        int r = 0;
        #pragma unroll
        for (int w = 0; w < 4; ++w) { int s = wsum[w]; woff[w] = r; r += s; }
        bsum[blockIdx.x] = r;
    }
    __syncthreads();
    int off = woff[wid] + excl;
    #pragma unroll
    for (int i = 0; i < 16; ++i)
        if (base + i < M) out[base + i] = v[i] + off;
}

__global__ void k_scan2(const int* __restrict__ bsum, int* __restrict__ boff, int NB) {
    __shared__ int wsum[4];
    __shared__ int woff[4];
    int t = threadIdx.x, lane = t & 63, wid = t >> 6;
    int x = (t < NB) ? bsum[t] : 0;
    int incl = wave_incl_scan(x, lane);
    int excl = incl - x;
    if (lane == 63) wsum[wid] = incl;
    __syncthreads();
    if (t == 0) {
        int r = 0;
        #pragma unroll
        for (int w = 0; w < 4; ++w) { int s = wsum[w]; woff[w] = r; r += s; }
    }
    __syncthreads();
    if (t < NB) boff[t] = woff[wid] + excl;
}

// ---- gemm body (64 rows x 128 cols per block), shared by fused kernels ----
__device__ __forceinline__ void gemm_body(SmemU& sm, const float* __restrict__ x,
                                          const unsigned short* __restrict__ Wtg,
                                          unsigned short* __restrict__ h,
                                          int row0, int N, int t) {
    int lane = t & 63, wid = t >> 6;
    {
        int r = t >> 2;
        int kseg = (t & 3) * 32;
        int gr = row0 + r;
        const float4* src = (const float4*)(x + (size_t)gr * 128 + kseg);
        #pragma unroll
        for (int i = 0; i < 4; ++i) {
            float4 v0 = make_float4(0.f, 0.f, 0.f, 0.f), v1 = v0;
            if (gr < N) { v0 = src[2 * i]; v1 = src[2 * i + 1]; }
            short8 p;
            p[0] = (short)f2bf(v0.x); p[1] = (short)f2bf(v0.y);
            p[2] = (short)f2bf(v0.z); p[3] = (short)f2bf(v0.w);
            p[4] = (short)f2bf(v1.x); p[5] = (short)f2bf(v1.y);
            p[6] = (short)f2bf(v1.z); p[7] = (short)f2bf(v1.w);
            *(short8*)&sm.g.Xs[r][kseg + 8 * i] = p;
        }
    }
    {
        int n = t >> 1;
        int seg = (t & 1) * 64;
        const short* wsrc = (const short*)Wtg + n * 128 + seg;
        #pragma unroll
        for (int i = 0; i < 8; ++i)
            *(short8*)&sm.g.Ws[n][seg + 8 * i] = *(const short8*)(wsrc + 8 * i);
    }
    __syncthreads();

    int q = lane >> 4;
    int m = lane & 15;
    f32x4 acc[8];
    #pragma unroll
    for (int tde = 0; tde < 8; ++tde) acc[tde] = (f32x4){0.f, 0.f, 0.f, 0.f};
    #pragma unroll
    for (int kc = 0; kc < 128; kc += 32) {
        short8 af = *(const short8*)&sm.g.Xs[wid * 16 + m][kc + q * 8];
        #pragma unroll
        for (int tde = 0; tde < 8; ++tde) {
            short8 bf = *(const short8*)&sm.g.Ws[tde * 16 + m][kc + q * 8];
            acc[tde] = __builtin_amdgcn_mfma_f32_16x16x32_bf16(af, bf, acc[tde], 0, 0, 0);
        }
    }
    #pragma unroll
    for (int r = 0; r < 4; ++r) {
        int grow = row0 + wid * 16 + q * 4 + r;
        if (grow < N) {
            #pragma unroll
            for (int tde = 0; tde < 8; ++tde)
                h[(size_t)grow * 128 + tde * 16 + m] = f2bf(acc[tde][r]);
        }
    }
}

// ---- fused: place (blocks [0,NBLK)) + gemm part A (blocks [NBLK, NBLK+GB1)) ----
__global__ __launch_bounds__(256) void k_pg(const int* __restrict__ row,
                                            const int* __restrict__ col,
                                            const float* __restrict__ wgt,
                                            const int* __restrict__ histg,
                                            const int* __restrict__ boff,
                                            int2* __restrict__ srw,
                                            const float* __restrict__ x,
                                            const unsigned short* __restrict__ Wtg,
                                            unsigned short* __restrict__ h,
                                            int E, int N, int NC, int NBLK) {
    __shared__ SmemU sm;
    int t = threadIdx.x;
    if ((int)blockIdx.x >= NBLK) {  // gemm branch
        gemm_body(sm, x, Wtg, h, ((int)blockIdx.x - NBLK) * 64, N, t);
        return;
    }
    int blk = blockIdx.x;
    int lane = t & 63, wid = t >> 6;
    int base = blk * CHUNK;
    int nE = min(CHUNK, E - base);
    for (int b = t; b < 1024; b += 256) sm.p.lcnt[b] = 0;
    __syncthreads();
    // pass A: local count
    #pragma unroll
    for (int i = 0; i < CHUNK / 256; ++i) {
        int e = base + i * 256 + t;
        if (e < E) atomicAdd(&sm.p.lcnt[col[e] >> 7], 1);
    }
    __syncthreads();
    // block-wide exclusive scan of lcnt[0..1024), 4 entries/thread
    int c4[4];
    int sum = 0;
    #pragma unroll
    for (int i = 0; i < 4; ++i) { int v = sm.p.lcnt[t * 4 + i]; c4[i] = sum; sum += v; }
    int incl = wave_incl_scan(sum, lane);
    int excl = incl - sum;
    if (lane == 63) sm.p.wsum[wid] = incl;
    __syncthreads();
    if (t == 0) {
        int r = 0;
        #pragma unroll
        for (int w = 0; w < 4; ++w) { int s = sm.p.wsum[w]; sm.p.woff[w] = r; r += s; }
    }
    __syncthreads();
    int tb = sm.p.woff[wid] + excl;
    __syncthreads();  // everyone has read woff/wsum; lcnt rewrite follows
    #pragma unroll
    for (int i = 0; i < 4; ++i) {
        int idx = t * 4 + i;
        int b0 = tb + c4[i];
        int gb = 0;
        if (idx < NC) {
            int g = idx * NBLK + blk;
            gb = histg[g] + boff[g >> SCAN_SHIFT];  // scan3 folded here
        }
        sm.p.gadj[idx] = gb - b0;
        sm.p.lcnt[idx] = b0;
    }
    __syncthreads();
    // pass B: scatter into LDS by bucket
    #pragma unroll
    for (int i = 0; i < CHUNK / 256; ++i) {
        int e = base + i * 256 + t;
        if (e < E) {
            int c = col[e];
            int slot = atomicAdd(&sm.p.lcnt[c >> 7], 1);
            sm.p.stage[slot] = make_int2(((c & 127) << 17) | row[e], __float_as_int(wgt[e]));
            sm.p.sdst[slot] = sm.p.gadj[c >> 7] + slot;
        }
    }
    __syncthreads();
    for (int s_ = t; s_ < nE; s_ += 256) {
        srw[sm.p.sdst[s_]] = sm.p.stage[s_];
    }
}

// ---- fused: fine (blocks [0,NC)) + gemm part B (blocks [NC, NC+GB2)) ----
__global__ __launch_bounds__(256) void k_fg(const int* __restrict__ histg,
                                            const int* __restrict__ boff,
                                            const int2* __restrict__ srw,
                                            int* __restrict__ rowptr,
                                            float* __restrict__ dis,
                                            int2* __restrict__ spack,
                                            const float* __restrict__ x,
                                            const unsigned short* __restrict__ Wtg,
                                            unsigned short* __restrict__ h,
                                            int E, int N, int NC, int NBLK, int GB1) {
    __shared__ SmemU sm;
    int t = threadIdx.x;
    if ((int)blockIdx.x >= NC) {  // gemm branch
        gemm_body(sm, x, Wtg, h, (GB1 + (int)blockIdx.x - NC) * 64, N, t);
        return;
    }
    int b = blockIdx.x;
    int nb = b << 7;
    int g0 = b * NBLK;
    int start = histg[g0] + boff[g0 >> SCAN_SHIFT];
    int end;
    if (b == NC - 1) end = E;
    else {
        int g1 = (b + 1) * NBLK;
        end = histg[g1] + boff[g1 >> SCAN_SHIFT];
    }
    int cnt = end - start;
    int NL = min(cnt, 3072);
    if (t < 128) { sm.f.cnt128[t] = 0; sm.f.degf[t] = 1.0f; }  // 1.0 = self-loop
    __syncthreads();
    // phase 1: single global read; stage first NL entries into LDS
    for (int j = t; j < cnt; j += 256) {
        int2 s = srw[start + j];
        if (j < NL) sm.f.sbuf[j] = s;
        int c = s.x >> 17;
        atomicAdd(&sm.f.cnt128[c], 1);
        atomicAdd(&sm.f.degf[c], __int_as_float(s.y));
    }
    __syncthreads();
    // phase 2: 128-entry exclusive scan, write rowptr/dis, seed cursors
    int v = 0, incl = 0;
    if (t < 128) {
        v = sm.f.cnt128[t];
        incl = wave_incl_scan(v, t & 63);
        if ((t & 63) == 63) sm.f.wtot[t >> 6] = incl;
    }
    __syncthreads();
    if (t < 128) {
        int excl = incl - v + ((t >= 64) ? sm.f.wtot[0] : 0);
        int p = start + excl;
        sm.f.cur128[t] = p;
        int n = nb + t;
        if (n < N) {
            rowptr[n] = p;
            dis[n] = rsqrtf(sm.f.degf[t]);
        }
    }
    if (t == 0 && b == NC - 1) rowptr[N] = E;
    __syncthreads();
    // phase 3: final placement from LDS (global for the rare overflow part)
    for (int j = t; j < cnt; j += 256) {
        int2 s = (j < NL) ? sm.f.sbuf[j] : srw[start + j];
        int c = s.x >> 17;
        int pos = atomicAdd(&sm.f.cur128[c], 1);
        spack[pos] = make_int2(s.x & 0x1FFFF, s.y);
    }
}

// ---- gather: R8/R4 1-wave-per-node, unroll-8 + software-pipelined spack ----
__global__ __launch_bounds__(256) void k_gather(const unsigned int* __restrict__ hb,
                                                const float* __restrict__ dis,
                                                const int* __restrict__ rowptr,
                                                const long* __restrict__ spackl,
                                                const float* __restrict__ bias,
                                                float* __restrict__ out, int N) {
    int gid = blockIdx.x * blockDim.x + threadIdx.x;
    int node = gid >> 6;
    int lane = gid & 63;
    if (node >= N) return;
    node = __builtin_amdgcn_readfirstlane(node);

    float dn = dis[node];
    unsigned u = hb[(size_t)node * 64 + lane];
    float2 acc;
    acc.x = dn * bf_lo(u);
    acc.y = dn * bf_hi(u);

    int jb = rowptr[node], je = rowptr[node + 1];
    int j = jb;
    long q0, q1, q2, q3, q4, q5, q6, q7;
    if (j + 8 <= je) {
        q0 = __builtin_nontemporal_load(spackl + j);
        q1 = __builtin_nontemporal_load(spackl + j + 1);
        q2 = __builtin_nontemporal_load(spackl + j + 2);
        q3 = __builtin_nontemporal_load(spackl + j + 3);
        q4 = __builtin_nontemporal_load(spackl + j + 4);
        q5 = __builtin_nontemporal_load(spackl + j + 5);
        q6 = __builtin_nontemporal_load(spackl + j + 6);
        q7 = __builtin_nontemporal_load(spackl + j + 7);
    }
    for (; j + 8 <= je; j += 8) {
        int r0 = __builtin_amdgcn_readfirstlane((int)q0);
        int r1 = __builtin_amdgcn_readfirstlane((int)q1);
        int r2 = __builtin_amdgcn_readfirstlane((int)q2);
        int r3 = __builtin_amdgcn_readfirstlane((int)q3);
        int r4 = __builtin_amdgcn_readfirstlane((int)q4);
        int r5 = __builtin_amdgcn_readfirstlane((int)q5);
        int r6 = __builtin_amdgcn_readfirstlane((int)q6);
        int r7 = __builtin_amdgcn_readfirstlane((int)q7);
        unsigned u0 = hb[(size_t)r0 * 64 + lane];
        unsigned u1 = hb[(size_t)r1 * 64 + lane];
        unsigned u2 = hb[(size_t)r2 * 64 + lane];
        unsigned u3 = hb[(size_t)r3 * 64 + lane];
        unsigned u4 = hb[(size_t)r4 * 64 + lane];
        unsigned u5 = hb[(size_t)r5 * 64 + lane];
        unsigned u6 = hb[(size_t)r6 * 64 + lane];
        unsigned u7 = hb[(size_t)r7 * 64 + lane];
        int jn = (j + 16 <= je) ? j + 8 : j;
        long n0 = __builtin_nontemporal_load(spackl + jn);
        long n1 = __builtin_nontemporal_load(spackl + jn + 1);
        long n2 = __builtin_nontemporal_load(spackl + jn + 2);
        long n3 = __builtin_nontemporal_load(spackl + jn + 3);
        long n4 = __builtin_nontemporal_load(spackl + jn + 4);
        long n5 = __builtin_nontemporal_load(spackl + jn + 5);
        long n6 = __builtin_nontemporal_load(spackl + jn + 6);
        long n7 = __builtin_nontemporal_load(spackl + jn + 7);
        float a0 = dis[r0] * __uint_as_float((unsigned)((unsigned long)q0 >> 32));
        float a1 = dis[r1] * __uint_as_float((unsigned)((unsigned long)q1 >> 32));
        float a2 = dis[r2] * __uint_as_float((unsigned)((unsigned long)q2 >> 32));
        float a3 = dis[r3] * __uint_as_float((unsigned)((unsigned long)q3 >> 32));
        float a4 = dis[r4] * __uint_as_float((unsigned)((unsigned long)q4 >> 32));
        float a5 = dis[r5] * __uint_as_float((unsigned)((unsigned long)q5 >> 32));
        float a6 = dis[r6] * __uint_as_float((unsigned)((unsigned long)q6 >> 32));
        float a7 = dis[r7] * __uint_as_float((unsigned)((unsigned long)q7 >> 32));
        acc.x = fmaf(a0, bf_lo(u0), acc.x); acc.y = fmaf(a0, bf_hi(u0), acc.y);
        acc.x = fmaf(a1, bf_lo(u1), acc.x); acc.y = fmaf(a1, bf_hi(u1), acc.y);
        acc.x = fmaf(a2, bf_lo(u2), acc.x); acc.y = fmaf(a2, bf_hi(u2), acc.y);
        acc.x = fmaf(a3, bf_lo(u3), acc.x); acc.y = fmaf(a3, bf_hi(u3), acc.y);
        acc.x = fmaf(a4, bf_lo(u4), acc.x); acc.y = fmaf(a4, bf_hi(u4), acc.y);
        acc.x = fmaf(a5, bf_lo(u5), acc.x); acc.y = fmaf(a5, bf_hi(u5), acc.y);
        acc.x = fmaf(a6, bf_lo(u6), acc.x); acc.y = fmaf(a6, bf_hi(u6), acc.y);
        acc.x = fmaf(a7, bf_lo(u7), acc.x); acc.y = fmaf(a7, bf_hi(u7), acc.y);
        q0 = n0; q1 = n1; q2 = n2; q3 = n3; q4 = n4; q5 = n5; q6 = n6; q7 = n7;
    }
    for (; j < je; ++j) {
        long q = __builtin_nontemporal_load(spackl + j);
        int r = __builtin_amdgcn_readfirstlane((int)q);
        unsigned uu = hb[(size_t)r * 64 + lane];
        float a = dis[r] * __uint_as_float((unsigned)((unsigned long)q >> 32));
        acc.x = fmaf(a, bf_lo(uu), acc.x);
        acc.y = fmaf(a, bf_hi(uu), acc.y);
    }

    int c0 = lane * 2;
    float2 bv = *(const float2*)(bias + c0);
    float2 o;
    o.x = bv.x + dn * acc.x;
    o.y = bv.y + dn * acc.y;
    union { float2 f; double d; } cvt;
    cvt.f = o;
    __builtin_nontemporal_store(cvt.d, (double*)(out + (size_t)node * 128 + c0));
}

extern "C" void kernel_launch(void* const* d_in, const int* in_sizes, int n_in,
                              void* d_out, int out_size, void* d_ws, size_t ws_size,
                              hipStream_t stream) {
    const float* x     = (const float*)d_in[0];
    const int*   eidx  = (const int*)d_in[1];   // [2,E] int32
    const float* eattr = (const float*)d_in[2];
    const float* W     = (const float*)d_in[3];
    const float* bias  = (const float*)d_in[4];
    int N = in_sizes[0] / 128;
    int E = in_sizes[2];
    const int* row = eidx;
    const int* col = eidx + E;

    int NC = (N + 127) >> 7;                       // 782 coarse buckets
    int NBLK = (E + CHUNK - 1) / CHUNK;            // 782 hist/place blocks

    char* p = (char*)d_ws;
    auto carve = [&](size_t bytes) {
        char* q = p;
        p += (bytes + 255) & ~(size_t)255;
        return q;
    };
    unsigned short* h   = (unsigned short*)carve((size_t)N * 128 * sizeof(unsigned short));
    unsigned short* Wtg = (unsigned short*)carve(128 * 128 * sizeof(unsigned short));
    float* dis    = (float*)carve((size_t)N * sizeof(float));
    int*   rowptr = (int*)carve((size_t)(N + 1) * sizeof(int));
    int*   histg  = (int*)carve((size_t)NC * NBLK * sizeof(int));
    int2*  srw    = (int2*)carve((size_t)E * sizeof(int2));
    int2*  spack  = (int2*)carve((size_t)E * sizeof(int2));
    int*   bsum   = (int*)carve(256 * sizeof(int));
    int*   boff   = (int*)carve(256 * sizeof(int));

    int M = NC * NBLK;
    int NBs = (M + ELEMS_PER_SCAN_BLOCK - 1) / ELEMS_PER_SCAN_BLOCK;  // 150 <= 256

    int GB  = (N + 63) / 64;   // 1563 gemm blocks total
    int GB1 = GB / 2;          // with place
    int GB2 = GB - GB1;        // with fine

    k_hist<<<NBLK, 256, 0, stream>>>(col, W, histg, Wtg, E, NC, NBLK);
    k_scan1<<<NBs, 256, 0, stream>>>(histg, histg, bsum, M);
    k_scan2<<<1, 256, 0, stream>>>(bsum, boff, NBs);
    k_pg<<<NBLK + GB1, 256, 0, stream>>>(row, col, eattr, histg, boff, srw,
                                         x, Wtg, h, E, N, NC, NBLK);
    k_fg<<<NC + GB2, 256, 0, stream>>>(histg, boff, srw, rowptr, dis, spack,
                                       x, Wtg, h, E, N, NC, NBLK, GB1);
    {
        size_t threads = (size_t)N * 64;
        int blocks = (int)((threads + 255) / 256);
        k_gather<<<blocks, 256, 0, stream>>>((const unsigned int*)h, dis, rowptr,
                                             (const long*)spack, bias, (float*)d_out, N);
    }
}